// Round 2
// baseline (326.209 us; speedup 1.0000x reference)
//
#include <hip/hip_runtime.h>
#include <stdint.h>

// ---------------------------------------------------------------------------
// MS_SSA_Conv: spiking self-attention. T=4 B=8 C=384 N=1024 heads=8.
// R2 changes vs R1:
//  * QKV weights: 2-part fp16 split (K=768) instead of 3-part bf16 (K=1152).
//    residual <= 2^-22 rel — below fp32 summation-order noise. -33% FLOPs.
//  * 128x128 tiles (m97 structure): 32 MFMA/wave per barrier-pair.
//  * qkv epilogue: direct ushort4 global stores (lane's 4 C-regs = 4
//    consecutive channels in [n][c] layout) — no LDS transpose.
//  * gate fused into proj: B-fragment AND with kvs mask (both {0,0x3F80}).
// ---------------------------------------------------------------------------

typedef unsigned short u16;
typedef __attribute__((ext_vector_type(8))) short short8v;
typedef __attribute__((ext_vector_type(4))) float f32x4;

#define AS1 __attribute__((address_space(1)))
#define AS3 __attribute__((address_space(3)))

__device__ __forceinline__ void async16(const void* g, void* l) {
    __builtin_amdgcn_global_load_lds((const AS1 unsigned int*)g,
                                     (AS3 unsigned int*)l, 16, 0, 0);
}
__device__ __forceinline__ f32x4 mfma_bf16(short8v a, short8v b, f32x4 c) {
    return __builtin_amdgcn_mfma_f32_16x16x32_bf16(a, b, c, 0, 0, 0);
}
__device__ __forceinline__ f32x4 mfma_f16(short8v a, short8v b, f32x4 c) {
    return __builtin_amdgcn_mfma_f32_16x16x32_f16(a, b, c, 0, 0, 0);
}

__device__ __forceinline__ u16 f2bf(float f) {  // RNE fp32->bf16
    uint32_t x = __float_as_uint(f);
    return (u16)((x + 0x7FFFu + ((x >> 16) & 1u)) >> 16);
}

#define SPIKE_H ((u16)0x3C00)  // fp16 1.0 (xs: qkv GEMM input)
#define SPIKE_B ((u16)0x3F80)  // bf16 1.0 (q/k/v spikes, kvs mask)

// ---------------------------------------------------------------------------
// K0: weights. Ah [1152 rows][768] fp16: rows = {q,k,v}x384 o; cols =
// 2 parts x 384 c (part-major). w = h0 + h1 + r, |r| <= 2^-22 |w|.
// Aproj [384][384] bf16 single-part.
// ---------------------------------------------------------------------------
__global__ void prep_kernel(const float* __restrict__ qw, const float* __restrict__ kw,
                            const float* __restrict__ vw, const float* __restrict__ pw,
                            u16* __restrict__ Ah, u16* __restrict__ Aproj) {
    int id = blockIdx.x * 256 + threadIdx.x;
    if (id >= 1152 * 384) return;
    int m = id / 384, c = id % 384;
    int br = m / 384, o = m % 384;
    const float* W = (br == 0) ? qw : (br == 1) ? kw : vw;
    float w = W[o * 384 + c];
    union H { _Float16 h; u16 u; } u0, u1;
    u0.h = (_Float16)w;
    float r1 = w - (float)u0.h;
    u1.h = (_Float16)r1;
    u16* row = Ah + (size_t)m * 768;
    row[c] = u0.u;
    row[384 + c] = u1.u;
    if (br == 0) Aproj[o * 384 + c] = f2bf(pw[o * 384 + c]);
}

// ---------------------------------------------------------------------------
// K1: shortcut LIF on x -> xs[t,b,n,c] fp16 spikes (c fastest).
// numpy op order: v += (x-v)*0.5 ; s = v>=0.5 ; v *= (1-s).
// ---------------------------------------------------------------------------
__global__ __launch_bounds__(256) void lifx_kernel(const float* __restrict__ x,
                                                   u16* __restrict__ xs) {
    __shared__ u16 Tr[64 * 72];
    int b = blockIdx.z, c0 = blockIdx.y * 64, n0 = blockIdx.x * 64;
    int tid = threadIdx.x;
    int nj = (tid & 15) * 4;
    int ci = tid >> 4;
    float v[4][4];
#pragma unroll
    for (int p = 0; p < 4; p++)
#pragma unroll
        for (int e = 0; e < 4; e++) v[p][e] = 0.0f;

    for (int t = 0; t < 4; t++) {
#pragma unroll
        for (int p = 0; p < 4; p++) {
            const float* src = x + ((size_t)((t * 8 + b) * 384 + c0 + p * 16 + ci)) * 1024 + n0 + nj;
            float4 xv = *(const float4*)src;
            float xa[4] = {xv.x, xv.y, xv.z, xv.w};
#pragma unroll
            for (int e = 0; e < 4; e++) {
                float vv = v[p][e];
                vv = __fadd_rn(vv, __fmul_rn(__fsub_rn(xa[e], vv), 0.5f));
                bool sp = (vv >= 0.5f);
                v[p][e] = sp ? 0.0f : vv;
                Tr[(nj + e) * 72 + p * 16 + ci] = sp ? SPIKE_H : (u16)0;
            }
        }
        __syncthreads();
#pragma unroll
        for (int p = 0; p < 4; p++) {
            int nr = p * 16 + (tid >> 4);
            int c4 = (tid & 15) * 4;
            *(ushort4*)(xs + ((size_t)((t * 8 + b) * 1024 + n0 + nr)) * 384 + c0 + c4) =
                *(const ushort4*)&Tr[nr * 72 + c4];
        }
        __syncthreads();
    }
}

// ---------------------------------------------------------------------------
// XOR-swizzled staging (shared by K2/K5): tile = 128 rows x 64 k = 1024
// chunks of 16B. slot l holds global chunk (row=l>>3, g=(l&7)^(row&7)).
// Fragment chunk g of row r lives at u16 offset r*64 + (g^(r&7))*8.
// ---------------------------------------------------------------------------

// K2: QKV conv (2-part fp16, K=768) + BN + LIF over t, membrane in regs.
// 128x128 (channel,pixel) tile per block; 4 waves each own 64x64 quadrant.
// grid (nt=8, mt=9, b=8). Spikes (bf16) -> {q,k,v}s[t,b,n,c].
__global__ __launch_bounds__(256, 2) void qkv_kernel(
    const u16* __restrict__ Ah, const u16* __restrict__ xs,
    u16* __restrict__ qs, u16* __restrict__ ks, u16* __restrict__ vs,
    const float* __restrict__ qg, const float* __restrict__ qb, const float* __restrict__ qm, const float* __restrict__ qv,
    const float* __restrict__ kg, const float* __restrict__ kb, const float* __restrict__ km, const float* __restrict__ kvr,
    const float* __restrict__ vg, const float* __restrict__ vb, const float* __restrict__ vm, const float* __restrict__ vvr) {
    __shared__ __align__(16) u16 At[8192];
    __shared__ __align__(16) u16 Bt[8192];
    __shared__ __align__(16) float bnS[128];
    __shared__ __align__(16) float bnM[128];
    __shared__ __align__(16) float bnB[128];

    int b = blockIdx.z, mt = blockIdx.y, nt = blockIdx.x;
    int m0 = mt * 128, n0 = nt * 128;
    int branch = mt / 3, o0 = (mt % 3) * 128;
    int tid = threadIdx.x, wave = tid >> 6, lane = tid & 63;
    int l15 = lane & 15, quad = lane >> 4;
    int wm = (wave & 1) * 64, wn = (wave >> 1) * 64;

    const float* g_ = (branch == 0) ? qg : (branch == 1) ? kg : vg;
    const float* be_ = (branch == 0) ? qb : (branch == 1) ? kb : vb;
    const float* m_ = (branch == 0) ? qm : (branch == 1) ? km : vm;
    const float* v_ = (branch == 0) ? qv : (branch == 1) ? kvr : vvr;
    u16* dstp = (branch == 0) ? qs : (branch == 1) ? ks : vs;

    if (tid < 128) {
        int o = o0 + tid;
        bnS[tid] = g_[o] / sqrtf(v_[o] + 1e-5f);
        bnM[tid] = m_[o];
        bnB[tid] = be_[o];
    }

    float vmem[4][4][4];
#pragma unroll
    for (int i = 0; i < 4; i++)
#pragma unroll
        for (int j = 0; j < 4; j++)
#pragma unroll
            for (int e = 0; e < 4; e++) vmem[i][j][e] = 0.0f;

    for (int t = 0; t < 4; t++) {
        f32x4 acc[4][4];
#pragma unroll
        for (int i = 0; i < 4; i++)
#pragma unroll
            for (int j = 0; j < 4; j++) acc[i][j] = (f32x4){0.f, 0.f, 0.f, 0.f};

        const u16* Bsrc = xs + ((size_t)((t * 8 + b) * 1024 + n0)) * 384;

        for (int kkb = 0; kkb < 12; kkb++) {
            int kk = kkb * 64;
            int ck = (kk >= 384) ? kk - 384 : kk;  // kk % 384 (part-major)
            __syncthreads();
#pragma unroll
            for (int ii = 0; ii < 4; ii++) {
                int l = ii * 256 + tid;
                int row = l >> 3;
                int cs = (l & 7) ^ (row & 7);
                async16(Ah + (size_t)(m0 + row) * 768 + kk + cs * 8, &At[l * 8]);
                async16(Bsrc + (size_t)row * 384 + ck + cs * 8, &Bt[l * 8]);
            }
            __syncthreads();
#pragma unroll
            for (int h = 0; h < 2; h++) {
                short8v af[4], bfr[4];
#pragma unroll
                for (int i = 0; i < 4; i++) {
                    int row = wm + i * 16 + l15;
                    int ch = (h * 4 + quad) ^ (row & 7);
                    af[i] = *(const short8v*)&At[row * 64 + ch * 8];
                }
#pragma unroll
                for (int j = 0; j < 4; j++) {
                    int nr = wn + j * 16 + l15;
                    int ch = (h * 4 + quad) ^ (nr & 7);
                    bfr[j] = *(const short8v*)&Bt[nr * 64 + ch * 8];
                }
#pragma unroll
                for (int i = 0; i < 4; i++)
#pragma unroll
                    for (int j = 0; j < 4; j++) acc[i][j] = mfma_f16(af[i], bfr[j], acc[i][j]);
            }
        }

        // epilogue: BN + LIF (exact numpy order) -> direct ushort4 stores
        size_t rb = (size_t)((t * 8 + b) * 1024 + n0);
#pragma unroll
        for (int i = 0; i < 4; i++) {
            int co = wm + i * 16 + quad * 4;
            float4 sc4 = *(const float4*)&bnS[co];
            float4 mn4 = *(const float4*)&bnM[co];
            float4 bt4 = *(const float4*)&bnB[co];
            float scA[4] = {sc4.x, sc4.y, sc4.z, sc4.w};
            float mnA[4] = {mn4.x, mn4.y, mn4.z, mn4.w};
            float btA[4] = {bt4.x, bt4.y, bt4.z, bt4.w};
#pragma unroll
            for (int j = 0; j < 4; j++) {
                int n = wn + j * 16 + l15;
                u16 sv[4];
#pragma unroll
                for (int e = 0; e < 4; e++) {
                    float a = acc[i][j][e];
                    a = __fadd_rn(__fmul_rn(__fsub_rn(a, mnA[e]), scA[e]), btA[e]);
                    float vv = vmem[i][j][e];
                    vv = __fadd_rn(vv, __fmul_rn(__fsub_rn(a, vv), 0.5f));
                    bool sp = (vv >= 0.5f);
                    vmem[i][j][e] = sp ? 0.0f : vv;
                    sv[e] = sp ? SPIKE_B : (u16)0;
                }
                ushort4 s4;
                s4.x = sv[0]; s4.y = sv[1]; s4.z = sv[2]; s4.w = sv[3];
                *(ushort4*)(dstp + (rb + n) * 384 + o0 + co) = s4;
            }
        }
        // next kkb's first __syncthreads orders epilogue before LDS restage
    }
}

// ---------------------------------------------------------------------------
// K3: kv[t,b,c] = sum_n k*v (exact integer counts; fp32 atomicAdd exact).
// ---------------------------------------------------------------------------
__global__ void kvred_kernel(const u16* __restrict__ ks, const u16* __restrict__ vs,
                             float* __restrict__ r) {
    int tb = blockIdx.y, nc = blockIdx.x, c = threadIdx.x;
    const u16* kp = ks + ((size_t)(tb * 1024 + nc * 64)) * 384 + c;
    const u16* vp = vs + ((size_t)(tb * 1024 + nc * 64)) * 384 + c;
    float cnt = 0.0f;
#pragma unroll 4
    for (int nn = 0; nn < 64; nn++) {
        u16 a = kp[(size_t)nn * 384];
        u16 bb = vp[(size_t)nn * 384];
        if ((a & bb) == SPIKE_B) cnt += 1.0f;
    }
    atomicAdd(&r[tb * 384 + c], cnt);
}

// K4: talking heads (8x8 fp32) + LIF over t -> kvs[t,b,c] bf16 {0,1} mask
__global__ void talking_kernel(const float* __restrict__ r, const float* __restrict__ th,
                               u16* __restrict__ kvs) {
    int id = blockIdx.x * 256 + threadIdx.x;
    if (id >= 8 * 384) return;
    int b = id / 384, c = id % 384;
    int oh = c / 48, d = c % 48;
    float v = 0.0f;
    for (int t = 0; t < 4; t++) {
        const float* rr = r + (t * 8 + b) * 384 + d;
        float s = 0.0f;
#pragma unroll
        for (int h = 0; h < 8; h++) s = __fmaf_rn(th[oh * 8 + h], rr[h * 48], s);
        v = __fadd_rn(v, __fmul_rn(__fsub_rn(s, v), 0.5f));
        bool sp = (v >= 0.5f);
        v = sp ? 0.0f : v;
        kvs[(t * 8 + b) * 384 + c] = sp ? SPIKE_B : (u16)0;
    }
}

// ---------------------------------------------------------------------------
// K5: proj conv (K=384 bf16) with FUSED kvs gate on B-frags + bias + BN +
// residual -> out fp32. 128x128 tiles, grid (nt=8, mt=3, tb=32).
// ---------------------------------------------------------------------------
__global__ __launch_bounds__(256) void proj_kernel(
    const u16* __restrict__ Aproj, const u16* __restrict__ qs, const u16* __restrict__ kvs,
    const float* __restrict__ xin,
    const float* __restrict__ pb, const float* __restrict__ pg, const float* __restrict__ pbe,
    const float* __restrict__ pm, const float* __restrict__ pv, float* __restrict__ out) {
    __shared__ __align__(16) u16 At[8192];
    __shared__ __align__(16) u16 Bt[8192];

    int tb = blockIdx.z, mt = blockIdx.y, nt = blockIdx.x;
    int m0 = mt * 128, n0 = nt * 128;
    int tid = threadIdx.x, wave = tid >> 6, lane = tid & 63;
    int l15 = lane & 15, quad = lane >> 4;
    int wm = (wave & 1) * 64, wn = (wave >> 1) * 64;

    f32x4 acc[4][4];
#pragma unroll
    for (int i = 0; i < 4; i++)
#pragma unroll
        for (int j = 0; j < 4; j++) acc[i][j] = (f32x4){0.f, 0.f, 0.f, 0.f};

    const u16* Bsrc = qs + ((size_t)(tb * 1024 + n0)) * 384;
    const u16* mbase = kvs + tb * 384;

    for (int kkb = 0; kkb < 6; kkb++) {
        int kk = kkb * 64;
        __syncthreads();
#pragma unroll
        for (int ii = 0; ii < 4; ii++) {
            int l = ii * 256 + tid;
            int row = l >> 3;
            int cs = (l & 7) ^ (row & 7);
            async16(Aproj + (size_t)(m0 + row) * 384 + kk + cs * 8, &At[l * 8]);
            async16(Bsrc + (size_t)row * 384 + kk + cs * 8, &Bt[l * 8]);
        }
        __syncthreads();
#pragma unroll
        for (int h = 0; h < 2; h++) {
            int g = h * 4 + quad;
            short8v msk = *(const short8v*)(mbase + kk + g * 8);  // {0,0x3F80} per c
            short8v af[4], bfr[4];
#pragma unroll
            for (int i = 0; i < 4; i++) {
                int row = wm + i * 16 + l15;
                int ch = g ^ (row & 7);
                af[i] = *(const short8v*)&At[row * 64 + ch * 8];
            }
#pragma unroll
            for (int j = 0; j < 4; j++) {
                int nr = wn + j * 16 + l15;
                int ch = g ^ (nr & 7);
                bfr[j] = *(const short8v*)&Bt[nr * 64 + ch * 8] & msk;  // gate q by kvs
            }
#pragma unroll
            for (int i = 0; i < 4; i++)
#pragma unroll
                for (int j = 0; j < 4; j++) acc[i][j] = mfma_bf16(af[i], bfr[j], acc[i][j]);
        }
    }

    // epilogue: y = conv+bias; (y-mean)*scale+beta; + identity (numpy order)
#pragma unroll
    for (int i = 0; i < 4; i++) {
#pragma unroll
        for (int e = 0; e < 4; e++) {
            int o = m0 + wm + i * 16 + quad * 4 + e;
            float scale = pg[o] / sqrtf(pv[o] + 1e-5f);
            float mean = pm[o], beta = pbe[o], bias = pb[o];
#pragma unroll
            for (int j = 0; j < 4; j++) {
                int n = n0 + wn + j * 16 + l15;
                size_t idx = ((size_t)tb * 384 + o) * 1024 + n;
                float y = __fadd_rn(acc[i][j][e], bias);
                y = __fadd_rn(__fmul_rn(__fsub_rn(y, mean), scale), beta);
                out[idx] = __fadd_rn(y, xin[idx]);
            }
        }
    }
}

// ---------------------------------------------------------------------------
extern "C" void kernel_launch(void* const* d_in, const int* in_sizes, int n_in,
                              void* d_out, int out_size, void* d_ws, size_t ws_size,
                              hipStream_t stream) {
    (void)in_sizes; (void)n_in; (void)out_size; (void)ws_size;
    const float* x  = (const float*)d_in[0];
    const float* qw = (const float*)d_in[1];
    const float* kw = (const float*)d_in[2];
    const float* vw = (const float*)d_in[3];
    const float* th = (const float*)d_in[4];
    const float* pw = (const float*)d_in[5];
    const float* pb = (const float*)d_in[6];
    const float* qg = (const float*)d_in[7],  *qbe = (const float*)d_in[8];
    const float* qm = (const float*)d_in[9],  *qv  = (const float*)d_in[10];
    const float* kg = (const float*)d_in[11], *kbe = (const float*)d_in[12];
    const float* km = (const float*)d_in[13], *kv_ = (const float*)d_in[14];
    const float* vg = (const float*)d_in[15], *vbe = (const float*)d_in[16];
    const float* vm = (const float*)d_in[17], *vv_ = (const float*)d_in[18];
    const float* pg = (const float*)d_in[19], *pbe = (const float*)d_in[20];
    const float* pm = (const float*)d_in[21], *pv  = (const float*)d_in[22];
    float* out = (float*)d_out;

    char* w = (char*)d_ws;
    const size_t SPIKES = (size_t)32 * 1024 * 384 * 2;  // 25,165,824 B each
    u16* xs    = (u16*)(w);
    u16* qs    = (u16*)(w + SPIKES);
    u16* ks    = (u16*)(w + 2 * SPIKES);
    u16* vs    = (u16*)(w + 3 * SPIKES);
    u16* Ah    = (u16*)(w + 4 * SPIKES);                         // 1,769,472 B
    u16* Aproj = (u16*)(w + 4 * SPIKES + 1769472);               //   294,912 B
    float* r   = (float*)(w + 4 * SPIKES + 1769472 + 294912);    //    49,152 B
    u16* kvs   = (u16*)(w + 4 * SPIKES + 1769472 + 294912 + 49152);  // 24,576 B

    hipMemsetAsync(r, 0, 32 * 384 * sizeof(float), stream);

    prep_kernel<<<1728, 256, 0, stream>>>(qw, kw, vw, pw, Ah, Aproj);
    lifx_kernel<<<dim3(16, 6, 8), 256, 0, stream>>>(x, xs);
    qkv_kernel<<<dim3(8, 9, 8), 256, 0, stream>>>(Ah, xs, qs, ks, vs,
                                                  qg, qbe, qm, qv,
                                                  kg, kbe, km, kv_,
                                                  vg, vbe, vm, vv_);
    kvred_kernel<<<dim3(16, 32), 384, 0, stream>>>(ks, vs, r);
    talking_kernel<<<12, 256, 0, stream>>>(r, th, kvs);
    proj_kernel<<<dim3(8, 3, 32), 256, 0, stream>>>(Aproj, qs, kvs, x, pb, pg, pbe, pm, pv, out);
}

// Round 3
// 294.542 us; speedup vs baseline: 1.1075x; 1.1075x over previous
//
#include <hip/hip_runtime.h>
#include <stdint.h>

// ---------------------------------------------------------------------------
// MS_SSA_Conv: spiking self-attention. T=4 B=8 C=384 N=1024 heads=8.
// R3 changes vs R2:
//  * qkv + proj GEMMs: double-buffered LDS, prefetch stage s+1 issued BEFORE
//    consuming stage s -> one barrier/stage, vmcnt drain overlaps MFMA.
//    (R2 was latency-bound: 48 serial 2-barrier stages, 2 blocks/CU.)
//  * kvred: 16B vector loads, 8 ch/thread, LDS pre-reduce (8x fewer loads).
// ---------------------------------------------------------------------------

typedef unsigned short u16;
typedef __attribute__((ext_vector_type(8))) short short8v;
typedef __attribute__((ext_vector_type(4))) float f32x4;

#define AS1 __attribute__((address_space(1)))
#define AS3 __attribute__((address_space(3)))

__device__ __forceinline__ void async16(const void* g, void* l) {
    __builtin_amdgcn_global_load_lds((const AS1 unsigned int*)g,
                                     (AS3 unsigned int*)l, 16, 0, 0);
}
__device__ __forceinline__ f32x4 mfma_bf16(short8v a, short8v b, f32x4 c) {
    return __builtin_amdgcn_mfma_f32_16x16x32_bf16(a, b, c, 0, 0, 0);
}
__device__ __forceinline__ f32x4 mfma_f16(short8v a, short8v b, f32x4 c) {
    return __builtin_amdgcn_mfma_f32_16x16x32_f16(a, b, c, 0, 0, 0);
}

__device__ __forceinline__ u16 f2bf(float f) {  // RNE fp32->bf16
    uint32_t x = __float_as_uint(f);
    return (u16)((x + 0x7FFFu + ((x >> 16) & 1u)) >> 16);
}

#define SPIKE_H ((u16)0x3C00)  // fp16 1.0 (xs)
#define SPIKE_B ((u16)0x3F80)  // bf16 1.0 (q/k/v spikes, kvs mask)

// ---------------------------------------------------------------------------
// K0: weights. Ah [1152][768] fp16 2-part split (part-major cols);
// Aproj [384][384] bf16.
// ---------------------------------------------------------------------------
__global__ void prep_kernel(const float* __restrict__ qw, const float* __restrict__ kw,
                            const float* __restrict__ vw, const float* __restrict__ pw,
                            u16* __restrict__ Ah, u16* __restrict__ Aproj) {
    int id = blockIdx.x * 256 + threadIdx.x;
    if (id >= 1152 * 384) return;
    int m = id / 384, c = id % 384;
    int br = m / 384, o = m % 384;
    const float* W = (br == 0) ? qw : (br == 1) ? kw : vw;
    float w = W[o * 384 + c];
    union H { _Float16 h; u16 u; } u0, u1;
    u0.h = (_Float16)w;
    float r1 = w - (float)u0.h;
    u1.h = (_Float16)r1;
    u16* row = Ah + (size_t)m * 768;
    row[c] = u0.u;
    row[384 + c] = u1.u;
    if (br == 0) Aproj[o * 384 + c] = f2bf(pw[o * 384 + c]);
}

// ---------------------------------------------------------------------------
// K1: shortcut LIF on x -> xs[t,b,n,c] fp16 spikes.
// ---------------------------------------------------------------------------
__global__ __launch_bounds__(256) void lifx_kernel(const float* __restrict__ x,
                                                   u16* __restrict__ xs) {
    __shared__ u16 Tr[64 * 72];
    int b = blockIdx.z, c0 = blockIdx.y * 64, n0 = blockIdx.x * 64;
    int tid = threadIdx.x;
    int nj = (tid & 15) * 4;
    int ci = tid >> 4;
    float v[4][4];
#pragma unroll
    for (int p = 0; p < 4; p++)
#pragma unroll
        for (int e = 0; e < 4; e++) v[p][e] = 0.0f;

    for (int t = 0; t < 4; t++) {
#pragma unroll
        for (int p = 0; p < 4; p++) {
            const float* src = x + ((size_t)((t * 8 + b) * 384 + c0 + p * 16 + ci)) * 1024 + n0 + nj;
            float4 xv = *(const float4*)src;
            float xa[4] = {xv.x, xv.y, xv.z, xv.w};
#pragma unroll
            for (int e = 0; e < 4; e++) {
                float vv = v[p][e];
                vv = __fadd_rn(vv, __fmul_rn(__fsub_rn(xa[e], vv), 0.5f));
                bool sp = (vv >= 0.5f);
                v[p][e] = sp ? 0.0f : vv;
                Tr[(nj + e) * 72 + p * 16 + ci] = sp ? SPIKE_H : (u16)0;
            }
        }
        __syncthreads();
#pragma unroll
        for (int p = 0; p < 4; p++) {
            int nr = p * 16 + (tid >> 4);
            int c4 = (tid & 15) * 4;
            *(ushort4*)(xs + ((size_t)((t * 8 + b) * 1024 + n0 + nr)) * 384 + c0 + c4) =
                *(const ushort4*)&Tr[nr * 72 + c4];
        }
        __syncthreads();
    }
}

// ---------------------------------------------------------------------------
// K2: QKV conv (2-part fp16, K=768) + BN + LIF over t, membrane in regs.
// 128x128 tile, dbuf LDS, 48 stages (t-major), 1 barrier/stage.
// grid (nt=8, mt=9, b=8).
// ---------------------------------------------------------------------------
__global__ __launch_bounds__(256, 2) void qkv_kernel(
    const u16* __restrict__ Ah, const u16* __restrict__ xs,
    u16* __restrict__ qs, u16* __restrict__ ks, u16* __restrict__ vs,
    const float* __restrict__ qg, const float* __restrict__ qb, const float* __restrict__ qm, const float* __restrict__ qv,
    const float* __restrict__ kg, const float* __restrict__ kb, const float* __restrict__ km, const float* __restrict__ kvr,
    const float* __restrict__ vg, const float* __restrict__ vb, const float* __restrict__ vm, const float* __restrict__ vvr) {
    __shared__ __align__(16) u16 At[2][8192];
    __shared__ __align__(16) u16 Bt[2][8192];
    __shared__ __align__(16) float bnS[128];
    __shared__ __align__(16) float bnM[128];
    __shared__ __align__(16) float bnB[128];

    int b = blockIdx.z, mt = blockIdx.y, nt = blockIdx.x;
    int m0 = mt * 128, n0 = nt * 128;
    int branch = mt / 3, o0 = (mt % 3) * 128;
    int tid = threadIdx.x, wave = tid >> 6, lane = tid & 63;
    int l15 = lane & 15, quad = lane >> 4;
    int wm = (wave & 1) * 64, wn = (wave >> 1) * 64;

    const float* g_ = (branch == 0) ? qg : (branch == 1) ? kg : vg;
    const float* be_ = (branch == 0) ? qb : (branch == 1) ? kb : vb;
    const float* m_ = (branch == 0) ? qm : (branch == 1) ? km : vm;
    const float* v_ = (branch == 0) ? qv : (branch == 1) ? kvr : vvr;
    u16* dstp = (branch == 0) ? qs : (branch == 1) ? ks : vs;

    if (tid < 128) {
        int o = o0 + tid;
        bnS[tid] = g_[o] / sqrtf(v_[o] + 1e-5f);
        bnM[tid] = m_[o];
        bnB[tid] = be_[o];
    }

    // stage s in [0,48): t = s/12, kkb = s%12. Buffer s&1.
    auto stage = [&](int s) {
        int st = s / 12, kkb = s % 12;
        int buf = s & 1;
        int kk = kkb * 64;
        int ck = (kk >= 384) ? kk - 384 : kk;
        const u16* Bsrc = xs + ((size_t)((st * 8 + b) * 1024 + n0)) * 384;
#pragma unroll
        for (int ii = 0; ii < 4; ii++) {
            int l = ii * 256 + tid;
            int row = l >> 3;
            int cs = (l & 7) ^ (row & 7);
            async16(Ah + (size_t)(m0 + row) * 768 + kk + cs * 8, &At[buf][l * 8]);
            async16(Bsrc + (size_t)row * 384 + ck + cs * 8, &Bt[buf][l * 8]);
        }
    };

    float vmem[4][4][4];
#pragma unroll
    for (int i = 0; i < 4; i++)
#pragma unroll
        for (int j = 0; j < 4; j++)
#pragma unroll
            for (int e = 0; e < 4; e++) vmem[i][j][e] = 0.0f;

    stage(0);
    __syncthreads();  // publishes stage 0 (drains vmcnt)

    for (int t = 0; t < 4; t++) {
        f32x4 acc[4][4];
#pragma unroll
        for (int i = 0; i < 4; i++)
#pragma unroll
            for (int j = 0; j < 4; j++) acc[i][j] = (f32x4){0.f, 0.f, 0.f, 0.f};

        for (int kkb = 0; kkb < 12; kkb++) {
            int s = t * 12 + kkb;
            int buf = s & 1;
            if (s + 1 < 48) stage(s + 1);  // prefetch into other buffer
#pragma unroll
            for (int h = 0; h < 2; h++) {
                short8v af[4], bfr[4];
#pragma unroll
                for (int i = 0; i < 4; i++) {
                    int row = wm + i * 16 + l15;
                    int ch = (h * 4 + quad) ^ (row & 7);
                    af[i] = *(const short8v*)&At[buf][row * 64 + ch * 8];
                }
#pragma unroll
                for (int j = 0; j < 4; j++) {
                    int nr = wn + j * 16 + l15;
                    int ch = (h * 4 + quad) ^ (nr & 7);
                    bfr[j] = *(const short8v*)&Bt[buf][nr * 64 + ch * 8];
                }
#pragma unroll
                for (int i = 0; i < 4; i++)
#pragma unroll
                    for (int j = 0; j < 4; j++) acc[i][j] = mfma_f16(af[i], bfr[j], acc[i][j]);
            }
            __syncthreads();  // waves done reading buf s; prefetch s+1 landed
        }

        // epilogue: BN + LIF (exact numpy order) -> direct ushort4 stores
        size_t rb = (size_t)((t * 8 + b) * 1024 + n0);
#pragma unroll
        for (int i = 0; i < 4; i++) {
            int co = wm + i * 16 + quad * 4;
            float4 sc4 = *(const float4*)&bnS[co];
            float4 mn4 = *(const float4*)&bnM[co];
            float4 bt4 = *(const float4*)&bnB[co];
            float scA[4] = {sc4.x, sc4.y, sc4.z, sc4.w};
            float mnA[4] = {mn4.x, mn4.y, mn4.z, mn4.w};
            float btA[4] = {bt4.x, bt4.y, bt4.z, bt4.w};
#pragma unroll
            for (int j = 0; j < 4; j++) {
                int n = wn + j * 16 + l15;
                u16 sv[4];
#pragma unroll
                for (int e = 0; e < 4; e++) {
                    float a = acc[i][j][e];
                    a = __fadd_rn(__fmul_rn(__fsub_rn(a, mnA[e]), scA[e]), btA[e]);
                    float vv = vmem[i][j][e];
                    vv = __fadd_rn(vv, __fmul_rn(__fsub_rn(a, vv), 0.5f));
                    bool sp = (vv >= 0.5f);
                    vmem[i][j][e] = sp ? 0.0f : vv;
                    sv[e] = sp ? SPIKE_B : (u16)0;
                }
                ushort4 s4;
                s4.x = sv[0]; s4.y = sv[1]; s4.z = sv[2]; s4.w = sv[3];
                *(ushort4*)(dstp + (rb + n) * 384 + o0 + co) = s4;
            }
        }
    }
}

// ---------------------------------------------------------------------------
// K3: kv[t,b,c] = sum_n k*v. 16B loads, 8 ch/thread, LDS pre-reduce.
// grid (nc=16, tb=32), 384 thr: tid = rr*48 + c8.
// ---------------------------------------------------------------------------
__global__ void kvred_kernel(const u16* __restrict__ ks, const u16* __restrict__ vs,
                             float* __restrict__ r) {
    __shared__ float red[384];
    int tb = blockIdx.y, nc = blockIdx.x;
    int tid = threadIdx.x;
    int rr = tid / 48, c8 = tid % 48;
    red[tid] = 0.0f;
    __syncthreads();

    float cnt[8];
#pragma unroll
    for (int e = 0; e < 8; e++) cnt[e] = 0.0f;

    size_t base = ((size_t)(tb * 1024 + nc * 64 + rr)) * 384 + c8 * 8;
#pragma unroll 2
    for (int it = 0; it < 8; it++) {
        size_t off = base + (size_t)it * 8 * 384;
        uint4 ka = *(const uint4*)(ks + off);
        uint4 va = *(const uint4*)(vs + off);
        uint32_t w0 = ka.x & va.x, w1 = ka.y & va.y, w2 = ka.z & va.z, w3 = ka.w & va.w;
        const uint32_t S = SPIKE_B;
        if ((w0 & 0xFFFFu) == S) cnt[0] += 1.0f;
        if ((w0 >> 16) == S)     cnt[1] += 1.0f;
        if ((w1 & 0xFFFFu) == S) cnt[2] += 1.0f;
        if ((w1 >> 16) == S)     cnt[3] += 1.0f;
        if ((w2 & 0xFFFFu) == S) cnt[4] += 1.0f;
        if ((w2 >> 16) == S)     cnt[5] += 1.0f;
        if ((w3 & 0xFFFFu) == S) cnt[6] += 1.0f;
        if ((w3 >> 16) == S)     cnt[7] += 1.0f;
    }
#pragma unroll
    for (int e = 0; e < 8; e++) atomicAdd(&red[c8 * 8 + e], cnt[e]);
    __syncthreads();
    atomicAdd(&r[tb * 384 + tid], red[tid]);
}

// K4: talking heads (8x8 fp32) + LIF over t -> kvs[t,b,c] bf16 {0,1} mask
__global__ void talking_kernel(const float* __restrict__ r, const float* __restrict__ th,
                               u16* __restrict__ kvs) {
    int id = blockIdx.x * 256 + threadIdx.x;
    if (id >= 8 * 384) return;
    int b = id / 384, c = id % 384;
    int oh = c / 48, d = c % 48;
    float v = 0.0f;
    for (int t = 0; t < 4; t++) {
        const float* rr = r + (t * 8 + b) * 384 + d;
        float s = 0.0f;
#pragma unroll
        for (int h = 0; h < 8; h++) s = __fmaf_rn(th[oh * 8 + h], rr[h * 48], s);
        v = __fadd_rn(v, __fmul_rn(__fsub_rn(s, v), 0.5f));
        bool sp = (v >= 0.5f);
        v = sp ? 0.0f : v;
        kvs[(t * 8 + b) * 384 + c] = sp ? SPIKE_B : (u16)0;
    }
}

// ---------------------------------------------------------------------------
// K5: proj conv (K=384 bf16) + fused kvs gate + bias + BN + residual.
// 128x128 tiles, dbuf LDS, grid (nt=8, mt=3, tb=32).
// ---------------------------------------------------------------------------
__global__ __launch_bounds__(256, 2) void proj_kernel(
    const u16* __restrict__ Aproj, const u16* __restrict__ qs, const u16* __restrict__ kvs,
    const float* __restrict__ xin,
    const float* __restrict__ pb, const float* __restrict__ pg, const float* __restrict__ pbe,
    const float* __restrict__ pm, const float* __restrict__ pv, float* __restrict__ out) {
    __shared__ __align__(16) u16 At[2][8192];
    __shared__ __align__(16) u16 Bt[2][8192];

    int tb = blockIdx.z, mt = blockIdx.y, nt = blockIdx.x;
    int m0 = mt * 128, n0 = nt * 128;
    int tid = threadIdx.x, wave = tid >> 6, lane = tid & 63;
    int l15 = lane & 15, quad = lane >> 4;
    int wm = (wave & 1) * 64, wn = (wave >> 1) * 64;

    const u16* Bsrc = qs + ((size_t)(tb * 1024 + n0)) * 384;
    const u16* mbase = kvs + tb * 384;

    auto stage = [&](int s) {
        int kk = s * 64;
        int buf = s & 1;
#pragma unroll
        for (int ii = 0; ii < 4; ii++) {
            int l = ii * 256 + tid;
            int row = l >> 3;
            int cs = (l & 7) ^ (row & 7);
            async16(Aproj + (size_t)(m0 + row) * 384 + kk + cs * 8, &At[buf][l * 8]);
            async16(Bsrc + (size_t)row * 384 + kk + cs * 8, &Bt[buf][l * 8]);
        }
    };

    f32x4 acc[4][4];
#pragma unroll
    for (int i = 0; i < 4; i++)
#pragma unroll
        for (int j = 0; j < 4; j++) acc[i][j] = (f32x4){0.f, 0.f, 0.f, 0.f};

    stage(0);
    __syncthreads();

    for (int kkb = 0; kkb < 6; kkb++) {
        int buf = kkb & 1;
        int kk = kkb * 64;
        if (kkb + 1 < 6) stage(kkb + 1);
#pragma unroll
        for (int h = 0; h < 2; h++) {
            int g = h * 4 + quad;
            short8v msk = *(const short8v*)(mbase + kk + g * 8);
            short8v af[4], bfr[4];
#pragma unroll
            for (int i = 0; i < 4; i++) {
                int row = wm + i * 16 + l15;
                int ch = g ^ (row & 7);
                af[i] = *(const short8v*)&At[buf][row * 64 + ch * 8];
            }
#pragma unroll
            for (int j = 0; j < 4; j++) {
                int nr = wn + j * 16 + l15;
                int ch = g ^ (nr & 7);
                bfr[j] = *(const short8v*)&Bt[buf][nr * 64 + ch * 8] & msk;  // gate
            }
#pragma unroll
            for (int i = 0; i < 4; i++)
#pragma unroll
                for (int j = 0; j < 4; j++) acc[i][j] = mfma_bf16(af[i], bfr[j], acc[i][j]);
        }
        __syncthreads();
    }

    // epilogue: y = conv+bias; (y-mean)*scale+beta; + identity (numpy order)
#pragma unroll
    for (int i = 0; i < 4; i++) {
#pragma unroll
        for (int e = 0; e < 4; e++) {
            int o = m0 + wm + i * 16 + quad * 4 + e;
            float scale = pg[o] / sqrtf(pv[o] + 1e-5f);
            float mean = pm[o], beta = pbe[o], bias = pb[o];
#pragma unroll
            for (int j = 0; j < 4; j++) {
                int n = n0 + wn + j * 16 + l15;
                size_t idx = ((size_t)tb * 384 + o) * 1024 + n;
                float y = __fadd_rn(acc[i][j][e], bias);
                y = __fadd_rn(__fmul_rn(__fsub_rn(y, mean), scale), beta);
                out[idx] = __fadd_rn(y, xin[idx]);
            }
        }
    }
}

// ---------------------------------------------------------------------------
extern "C" void kernel_launch(void* const* d_in, const int* in_sizes, int n_in,
                              void* d_out, int out_size, void* d_ws, size_t ws_size,
                              hipStream_t stream) {
    (void)in_sizes; (void)n_in; (void)out_size; (void)ws_size;
    const float* x  = (const float*)d_in[0];
    const float* qw = (const float*)d_in[1];
    const float* kw = (const float*)d_in[2];
    const float* vw = (const float*)d_in[3];
    const float* th = (const float*)d_in[4];
    const float* pw = (const float*)d_in[5];
    const float* pb = (const float*)d_in[6];
    const float* qg = (const float*)d_in[7],  *qbe = (const float*)d_in[8];
    const float* qm = (const float*)d_in[9],  *qv  = (const float*)d_in[10];
    const float* kg = (const float*)d_in[11], *kbe = (const float*)d_in[12];
    const float* km = (const float*)d_in[13], *kv_ = (const float*)d_in[14];
    const float* vg = (const float*)d_in[15], *vbe = (const float*)d_in[16];
    const float* vm = (const float*)d_in[17], *vv_ = (const float*)d_in[18];
    const float* pg = (const float*)d_in[19], *pbe = (const float*)d_in[20];
    const float* pm = (const float*)d_in[21], *pv  = (const float*)d_in[22];
    float* out = (float*)d_out;

    char* w = (char*)d_ws;
    const size_t SPIKES = (size_t)32 * 1024 * 384 * 2;  // 25,165,824 B each
    u16* xs    = (u16*)(w);
    u16* qs    = (u16*)(w + SPIKES);
    u16* ks    = (u16*)(w + 2 * SPIKES);
    u16* vs    = (u16*)(w + 3 * SPIKES);
    u16* Ah    = (u16*)(w + 4 * SPIKES);                         // 1,769,472 B
    u16* Aproj = (u16*)(w + 4 * SPIKES + 1769472);               //   294,912 B
    float* r   = (float*)(w + 4 * SPIKES + 1769472 + 294912);    //    49,152 B
    u16* kvs   = (u16*)(w + 4 * SPIKES + 1769472 + 294912 + 49152);  // 24,576 B

    hipMemsetAsync(r, 0, 32 * 384 * sizeof(float), stream);

    prep_kernel<<<1728, 256, 0, stream>>>(qw, kw, vw, pw, Ah, Aproj);
    lifx_kernel<<<dim3(16, 6, 8), 256, 0, stream>>>(x, xs);
    qkv_kernel<<<dim3(8, 9, 8), 256, 0, stream>>>(Ah, xs, qs, ks, vs,
                                                  qg, qbe, qm, qv,
                                                  kg, kbe, km, kv_,
                                                  vg, vbe, vm, vv_);
    kvred_kernel<<<dim3(16, 32), 384, 0, stream>>>(ks, vs, r);
    talking_kernel<<<12, 256, 0, stream>>>(r, th, kvs);
    proj_kernel<<<dim3(8, 3, 32), 256, 0, stream>>>(Aproj, qs, kvs, x, pb, pg, pbe, pm, pv, out);
}